// Round 9
// baseline (817.711 us; speedup 1.0000x reference)
//
#include <hip/hip_runtime.h>

// SimpleRNN: T=64, B=8, H=512, I=256, O=8, G=4, GS=64
// sign: +1 for j<=408, -1 for j>=409; exist: j<410
// chunk c: j = lane + 64c. c<=5 -> +1; c==7 -> -1 (exist=0);
// c==6 -> lane<=24: +1, lane==25: -1 (exists), lane>=26: no exist.
#define T_N 64
#define B_N 8
#define H_N 512
#define I_N 256
#define O_N 8
#define G_N 4

constexpr float DT_  = 0.02f;
constexpr float AX_  = 0.2f;    // DT/0.1
constexpr float AW_  = 0.02f;   // DT/1.0
constexpr float OMAW = 1.0f - AW_;

using u32 = unsigned;
using u64 = unsigned long long;

// Agent-scope (sc0+sc1): bypass L1 and L2, coherent at the MALL/LLC.
__device__ __forceinline__ u64 ld64_agent(const u64* p) {
    return __hip_atomic_load(p, __ATOMIC_RELAXED, __HIP_MEMORY_SCOPE_AGENT);
}
__device__ __forceinline__ void st64_agent(u64* p, u64 v) {
    __hip_atomic_store(p, v, __ATOMIC_RELAXED, __HIP_MEMORY_SCOPE_AGENT);
}

// XCD-local (sc0 only): bypass L1, coherent at the XCD's shared L2.
// HIP has no XCD memory scope, so inline asm. Load waits its own vmcnt.
__device__ __forceinline__ u64 ld64_sc0(const u64* p) {
    u64 r;
    asm volatile("global_load_dwordx2 %0, %1, off sc0\n\t"
                 "s_waitcnt vmcnt(0)"
                 : "=v"(r) : "v"(p) : "memory");
    return r;
}
__device__ __forceinline__ void st64_sc0(u64* p, u64 v) {
    asm volatile("global_store_dwordx2 %0, %1, off sc0"
                 :: "v"(p), "v"(v) : "memory");
}

__device__ __forceinline__ float fast_tanh_pos(float x) {
    // x >= 0; exact at 0 and +inf. tanh(x) = 1 - 2/(e^{2x}+1)
    float ex = __expf(2.0f * x);
    return 1.0f - 2.0f / (ex + 1.0f);
}

// 256 blocks x 1024 threads; wave owns one h. b = bk&7 (round-robin puts all
// 32 blocks of a batch on one XCD), hg = bk>>3, h = hg*16 + wid.
// Per step: producer lane0 dual-publishes a tagged u64 ((t+1)<<32|bits):
//   sc0 store -> XCD-local L2 buffer  (fast path signal+value)
//   agent store -> MALL buffer        (fallback, always correct)
// Wave 0 polls local lines (lane L -> line L = h 8L..8L+7; 32 intra-XCD
// streams/line); lanes that time out go sticky-remote and poll the agent
// buffer. Absolute tags reject any stale copy. One LDS barrier per step.
__global__ __launch_bounds__(1024) void rnn_scan(
    const float* __restrict__ x, const float* __restrict__ Rs,
    const float* __restrict__ W_x2h, const float* __restrict__ W_h2h,
    const float* __restrict__ b_h2h,
    const float* __restrict__ W_attn, const float* __restrict__ b_attn,
    const float* __restrict__ kappa, float* __restrict__ hs,
    u64* __restrict__ lvals,           // [2][B][H] tagged u64 (XCD-local)
    u64* __restrict__ avals)           // [2][B][H] tagged u64 (agent)
{
    __shared__ float s_out[2][H_N];    // double buffer: 1 barrier/step

    const int tid  = threadIdx.x;
    const int wid  = tid >> 6;         // 0..15
    const int lane = tid & 63;
    const int bk   = blockIdx.x;       // 0..255
    const int b    = bk & 7;
    const int hg   = bk >> 3;          // 0..31
    const int h    = (hg << 4) | wid;  // 0..511
    const int c_d  = h >> 6;           // chunk holding the diagonal
    const int dl   = h & 63;           // its lane

    // ---- loop-invariant constants (registers only) ----
    float ea[G_N][7];
#pragma unroll
    for (int g = 0; g < G_N; ++g)
#pragma unroll
        for (int c = 0; c < 7; ++c) {
            int j = lane + 64 * c;
            float w = fmaxf(W_attn[g * H_N + j], 0.0f);
            float m = (j <= 408) ? 1.0f : ((j == 409) ? -1.0f : 0.0f);
            ea[g][c] = w * m;
        }

    // x-side: ex = Wxp + wx (>=0); bwx = AW*Wxp
    float ex[4], bwx[4];
#pragma unroll
    for (int c = 0; c < 4; ++c) {
        ex[c]  = fmaxf(W_x2h[h * I_N + lane + 64 * c], 0.0f);
        bwx[c] = AW_ * ex[c];
    }
    // h2h: se = sign*(Whp+wh); bwh = AW*Whp
    float se[8], bwh[8];
#pragma unroll
    for (int c = 0; c < 8; ++c) {
        int j = lane + 64 * c;
        float s = (j <= 408) ? 1.0f : -1.0f;
        float w = fmaxf(W_h2h[h * H_N + j], 0.0f);
        se[c]  = (j == h) ? 0.0f : s * w;
        bwh[c] = AW_ * w;
    }
    const float bh = b_h2h[h];
    const float k0 = kappa[0], k1 = kappa[1], k2 = kappa[2];
    const float k3 = kappa[3], k4 = kappa[4], k5 = kappa[5];
    const float ba0 = b_attn[0], ba1 = b_attn[1], ba2 = b_attn[2], ba3 = b_attn[3];

    float st = 0.0f;

    float xv[4];
#pragma unroll
    for (int c = 0; c < 4; ++c) xv[c] = fmaxf(x[(size_t)b * I_N + lane + 64 * c], 0.0f);
    float Rcur = Rs[b];

    float outp[8];
#pragma unroll
    for (int c = 0; c < 8; ++c) outp[c] = 0.0f;   // t=0 inputs are zeros

    u32 remote_mask = 0;   // wave-0 sticky fallback state (per lane)

    for (int t = 0; t < T_N; ++t) {
        // ---- 9 fused wave reductions: 4 attn logits, 4 x-dot group
        //      partials, 1 h2h dot ----
        float red[9];
#pragma unroll
        for (int g = 0; g < G_N; ++g) {
            float l = 0.0f;
#pragma unroll
            for (int c = 0; c < 7; ++c) l = fmaf(outp[c], ea[g][c], l);
            red[g] = l;
        }
#pragma unroll
        for (int c = 0; c < 4; ++c) red[4 + c] = ex[c] * xv[c];
        {
            float a = 0.0f;
#pragma unroll
            for (int c = 0; c < 8; ++c) a = fmaf(se[c], outp[c], a);
            red[8] = a;
        }
#pragma unroll
        for (int off = 32; off >= 1; off >>= 1) {
#pragma unroll
            for (int k = 0; k < 9; ++k) red[k] += __shfl_xor(red[k], off, 64);
        }

        // ---- softmax over 4 logits (bounded, no max-shift needed) ----
        float e0 = __expf(red[0] + ba0), e1 = __expf(red[1] + ba1);
        float e2 = __expf(red[2] + ba2), e3 = __expf(red[3] + ba3);
        float inv = 4.0f / (e0 + e1 + e2 + e3);     // fold *G
        float aw0 = e0 * inv, aw1 = e1 * inv, aw2 = e2 * inv, aw3 = e3 * inv;

        float total = red[4] * aw0 + red[5] * aw1 + red[6] * aw2 + red[7] * aw3
                    + red[8] + bh;

        st = st * (1.0f - AX_) + total * AX_;
        float no = fast_tanh_pos(fmaxf(st, 0.0f));

        // ---- dual publish: value IS the signal, fire-and-forget ----
        u64* lrow = lvals + ((size_t)(t & 1) * B_N + b) * H_N;
        u64* arow = avals + ((size_t)(t & 1) * B_N + b) * H_N;
        if (lane == 0) {
            hs[((size_t)t * B_N + b) * H_N + h] = no;   // plain, for os_proj
            if (t + 1 < T_N) {
                u64 tg = ((u64)(u32)(t + 1) << 32) | (u64)__float_as_uint(no);
                st64_sc0(lrow + h, tg);    // XCD-local fast path
                st64_agent(arow + h, tg);  // MALL fallback
            }
        }

        if (t + 1 == T_N) break;   // last step: epilogue kernel handles os

        // ---- next-step input prefetch + plasticity (stores in flight) ----
        const float* xr = x + ((size_t)(t + 1) * B_N + b) * I_N;
        float xvn[4];
#pragma unroll
        for (int c = 0; c < 4; ++c) xvn[c] = xr[lane + 64 * c];
        float Rn = Rs[(t + 1) * B_N + b];

        float xin[4] = { xv[0] * aw0, xv[1] * aw1, xv[2] * aw2, xv[3] * aw3 };
        float dr = DT_ * Rcur;
        float k1n = k1 * no, k2n = k2 * no, k4n = k4 * no, k5n = k5 * no;
#pragma unroll
        for (int c = 0; c < 4; ++c) {
            float hx = fmaf(k2n, xin[c], fmaf(k0, xin[c], k1n));
            ex[c] = fmaxf(fmaf(ex[c], OMAW, fmaf(dr, hx, bwx[c])), 0.0f);
        }
#pragma unroll
        for (int c = 0; c < 8; ++c) {
            float hh = fmaf(k5n, outp[c], fmaf(k3, outp[c], k4n));
            float a = se[c] * OMAW, p = fmaf(dr, hh, bwh[c]);
            float r;
            if (c <= 5)      r = fmaxf(a + p, 0.0f);
            else if (c == 7) r = fminf(a - p, 0.0f);
            else             r = (lane <= 24) ? fmaxf(a + p, 0.0f)
                                              : fminf(a - p, 0.0f);
            if (c == c_d && lane == dl) r = 0.0f;   // keep diagonal at 0
            se[c] = r;
        }

        // ---- wave 0: poll own line (h 8*lane..8*lane+7) ----
        if (wid == 0) {
            const u32 want = (u32)(t + 1);
            const u64* lline = lrow + (lane << 3);
            const u64* aline = arow + (lane << 3);
            float v[8];
            u32 done = 0;
            int k = 0;
            while (true) {
#pragma unroll
                for (int c = 0; c < 8; ++c) {
                    if (!((done >> c) & 1u)) {
                        bool rem = (remote_mask >> c) & 1u;
                        u64 pk = rem ? ld64_agent(aline + c) : ld64_sc0(lline + c);
                        if ((u32)(pk >> 32) == want) {
                            v[c] = __uint_as_float((u32)pk);
                            done |= (1u << c);
                        }
                    }
                }
                if (__all(done == 0xFFu)) break;
                ++k;
                if (k == 24) remote_mask |= (~done) & 0xFFu;  // sticky fallback
                if (k >= 4) __builtin_amdgcn_s_sleep(1);
            }
            float* sb = s_out[t & 1];
#pragma unroll
            for (int c = 0; c < 8; ++c) sb[(lane << 3) + c] = v[c];
        }
        __syncthreads();   // single barrier/step (double-buffered s_out)

        const float* sb = s_out[t & 1];
#pragma unroll
        for (int c = 0; c < 8; ++c) outp[c] = sb[lane + 64 * c];
#pragma unroll
        for (int c = 0; c < 4; ++c) xv[c] = fmaxf(xvn[c], 0.0f);
        Rcur = Rn;
    }
}

// os[t,b,o] = sum_h hs[t,b,h] * relu(W_h2o[o,h]) * exist[h]
// Separate launch: kernel boundary (dispatch-complete release + launch
// acquire) makes the plain hs stores visible to plain loads (R8-validated).
__global__ __launch_bounds__(512) void os_proj(
    const float* __restrict__ hs, const float* __restrict__ W_h2o,
    float* __restrict__ os)
{
    const int blk  = blockIdx.x;        // 0..511
    const int t    = blk >> 3;
    const int b    = blk & 7;
    const int o    = threadIdx.x >> 6;  // 0..7
    const int lane = threadIdx.x & 63;
    const float* hrow = hs + ((size_t)t * B_N + b) * H_N;
    float acc = 0.0f;
#pragma unroll
    for (int c = 0; c < 7; ++c) {       // c==7 has no exist
        int j = lane + 64 * c;
        float w = fmaxf(W_h2o[o * H_N + j], 0.0f);
        if (j >= 410) w = 0.0f;
        acc = fmaf(hrow[j], w, acc);
    }
#pragma unroll
    for (int off = 32; off >= 1; off >>= 1) acc += __shfl_xor(acc, off, 64);
    if (lane == 0) os[t * (B_N * O_N) + b * O_N + o] = acc;
}

extern "C" void kernel_launch(void* const* d_in, const int* in_sizes, int n_in,
                              void* d_out, int out_size, void* d_ws, size_t ws_size,
                              hipStream_t stream) {
    (void)in_sizes; (void)n_in; (void)out_size; (void)ws_size;
    const float* x      = (const float*)d_in[0];
    const float* Rs     = (const float*)d_in[1];
    const float* W_x2h  = (const float*)d_in[2];
    const float* W_h2h  = (const float*)d_in[3];
    const float* b_h2h  = (const float*)d_in[4];
    const float* W_h2o  = (const float*)d_in[5];
    const float* W_attn = (const float*)d_in[6];
    const float* b_attn = (const float*)d_in[7];
    const float* kappa  = (const float*)d_in[8];
    float* os = (float*)d_out;                       // [T][B][O]
    float* hs = (float*)d_out + T_N * B_N * O_N;     // [T][B][H]

    u64* lvals = (u64*)d_ws;                         // [2][8][512] u64 = 64 KB
    u64* avals = (u64*)((char*)d_ws + 65536);        // [2][8][512] u64 = 64 KB

    // zero both tagged buffers every call (tag 0 != any wanted tag 1..63)
    hipMemsetAsync(d_ws, 0, 2 * 65536, stream);
    rnn_scan<<<dim3(256), dim3(1024), 0, stream>>>(
        x, Rs, W_x2h, W_h2h, b_h2h, W_attn, b_attn, kappa, hs, lvals, avals);
    os_proj<<<dim3(512), dim3(512), 0, stream>>>(hs, W_h2o, os);
}

// Round 10
// 368.188 us; speedup vs baseline: 2.2209x; 2.2209x over previous
//
#include <hip/hip_runtime.h>

// SimpleRNN: T=64, B=8, H=512, I=256, O=8, G=4, GS=64
// sign: +1 for j<=408, -1 for j>=409; exist: j<410
// chunk c: j = lane + 64c. c<=5 -> +1; c==7 -> -1 (exist=0);
// c==6 -> lane<=24: +1, lane==25: -1 (exists), lane>=26: no exist.
#define T_N 64
#define B_N 8
#define H_N 512
#define I_N 256
#define O_N 8
#define G_N 4

// comm slot stride: one 128B-exclusive line per h (16 u64)
#define VSTRIDE 16

constexpr float DT_  = 0.02f;
constexpr float AX_  = 0.2f;    // DT/0.1
constexpr float AW_  = 0.02f;   // DT/1.0
constexpr float OMAW = 1.0f - AW_;

using u32 = unsigned;
using u64 = unsigned long long;

// Agent-scope coherent ops (sc0/sc1): bypass non-coherent L1/L2 -> MALL.
__device__ __forceinline__ u64 ld64_agent(const u64* p) {
    return __hip_atomic_load(p, __ATOMIC_RELAXED, __HIP_MEMORY_SCOPE_AGENT);
}
__device__ __forceinline__ void st64_agent(u64* p, u64 v) {
    __hip_atomic_store(p, v, __ATOMIC_RELAXED, __HIP_MEMORY_SCOPE_AGENT);
}

__device__ __forceinline__ float fast_tanh_pos(float x) {
    // x >= 0; exact at 0 and +inf. tanh(x) = 1 - 2/(e^{2x}+1)
    float ex = __expf(2.0f * x);
    return 1.0f - 2.0f / (ex + 1.0f);
}

// 256 blocks x 1024 threads; wave owns one h. b = bk&7, hg = bk>>3,
// h = hg*16 + wid. Per-step cross-block sync: producer lane0 fires ONE
// tagged u64 ((t+1)<<32 | f32bits) into its h's PRIVATE 128B line
// (1 writer/line, written once per slot period -- the line-exclusivity
// law from R5 vs R8). Consumer: wave 0 only; lane L polls h = L+64c
// (32 poll streams/line), done-mask + s_sleep backoff, batched loads.
// Relay via double-buffered LDS, 1 barrier/step.
__global__ __launch_bounds__(1024) void rnn_scan(
    const float* __restrict__ x, const float* __restrict__ Rs,
    const float* __restrict__ W_x2h, const float* __restrict__ W_h2h,
    const float* __restrict__ b_h2h,
    const float* __restrict__ W_attn, const float* __restrict__ b_attn,
    const float* __restrict__ kappa, float* __restrict__ hs,
    u64* __restrict__ vals)            // [2][B][H][VSTRIDE] u64
{
    __shared__ float s_out[2][H_N];    // double buffer: 1 barrier/step

    const int tid  = threadIdx.x;
    const int wid  = tid >> 6;         // 0..15
    const int lane = tid & 63;
    const int bk   = blockIdx.x;       // 0..255
    const int b    = bk & 7;
    const int hg   = bk >> 3;          // 0..31
    const int h    = (hg << 4) | wid;  // 0..511
    const int c_d  = h >> 6;           // chunk holding the diagonal
    const int dl   = h & 63;           // its lane

    // ---- loop-invariant constants (registers only) ----
    float ea[G_N][7];
#pragma unroll
    for (int g = 0; g < G_N; ++g)
#pragma unroll
        for (int c = 0; c < 7; ++c) {
            int j = lane + 64 * c;
            float w = fmaxf(W_attn[g * H_N + j], 0.0f);
            float m = (j <= 408) ? 1.0f : ((j == 409) ? -1.0f : 0.0f);
            ea[g][c] = w * m;
        }

    // x-side: ex = Wxp + wx (>=0); bwx = AW*Wxp
    float ex[4], bwx[4];
#pragma unroll
    for (int c = 0; c < 4; ++c) {
        ex[c]  = fmaxf(W_x2h[h * I_N + lane + 64 * c], 0.0f);
        bwx[c] = AW_ * ex[c];
    }
    // h2h: se = sign*(Whp+wh); bwh = AW*Whp
    float se[8], bwh[8];
#pragma unroll
    for (int c = 0; c < 8; ++c) {
        int j = lane + 64 * c;
        float s = (j <= 408) ? 1.0f : -1.0f;
        float w = fmaxf(W_h2h[h * H_N + j], 0.0f);
        se[c]  = (j == h) ? 0.0f : s * w;
        bwh[c] = AW_ * w;
    }
    const float bh = b_h2h[h];
    const float k0 = kappa[0], k1 = kappa[1], k2 = kappa[2];
    const float k3 = kappa[3], k4 = kappa[4], k5 = kappa[5];
    const float ba0 = b_attn[0], ba1 = b_attn[1], ba2 = b_attn[2], ba3 = b_attn[3];

    float st = 0.0f;

    float xv[4];
#pragma unroll
    for (int c = 0; c < 4; ++c) xv[c] = fmaxf(x[(size_t)b * I_N + lane + 64 * c], 0.0f);
    float Rcur = Rs[b];

    float outp[8];
#pragma unroll
    for (int c = 0; c < 8; ++c) outp[c] = 0.0f;   // t=0 inputs are zeros

    for (int t = 0; t < T_N; ++t) {
        // ---- 9 fused wave reductions: 4 attn logits, 4 x-dot group
        //      partials, 1 h2h dot ----
        float red[9];
#pragma unroll
        for (int g = 0; g < G_N; ++g) {
            float l = 0.0f;
#pragma unroll
            for (int c = 0; c < 7; ++c) l = fmaf(outp[c], ea[g][c], l);
            red[g] = l;
        }
#pragma unroll
        for (int c = 0; c < 4; ++c) red[4 + c] = ex[c] * xv[c];
        {
            float a = 0.0f;
#pragma unroll
            for (int c = 0; c < 8; ++c) a = fmaf(se[c], outp[c], a);
            red[8] = a;
        }
#pragma unroll
        for (int off = 32; off >= 1; off >>= 1) {
#pragma unroll
            for (int k = 0; k < 9; ++k) red[k] += __shfl_xor(red[k], off, 64);
        }

        // ---- softmax over 4 logits (bounded, no max-shift needed) ----
        float e0 = __expf(red[0] + ba0), e1 = __expf(red[1] + ba1);
        float e2 = __expf(red[2] + ba2), e3 = __expf(red[3] + ba3);
        float inv = 4.0f / (e0 + e1 + e2 + e3);     // fold *G
        float aw0 = e0 * inv, aw1 = e1 * inv, aw2 = e2 * inv, aw3 = e3 * inv;

        float total = red[4] * aw0 + red[5] * aw1 + red[6] * aw2 + red[7] * aw3
                    + red[8] + bh;

        st = st * (1.0f - AX_) + total * AX_;
        float no = fast_tanh_pos(fmaxf(st, 0.0f));

        // ---- publish: plain hs store (off critical path) + ONE tagged
        //      agent store into h's private line, fire-and-forget ----
        u64* vrow = vals + ((size_t)(t & 1) * B_N + b) * H_N * VSTRIDE;
        if (lane == 0) {
            hs[((size_t)t * B_N + b) * H_N + h] = no;   // plain, cached
            if (t + 1 < T_N)
                st64_agent(vrow + (size_t)h * VSTRIDE,
                           ((u64)(u32)(t + 1) << 32) | (u64)__float_as_uint(no));
        }

        if (t + 1 == T_N) break;   // last step: epilogue kernel handles os

        // ---- next-step input prefetch + plasticity (store in flight) ----
        const float* xr = x + ((size_t)(t + 1) * B_N + b) * I_N;
        float xvn[4];
#pragma unroll
        for (int c = 0; c < 4; ++c) xvn[c] = xr[lane + 64 * c];
        float Rn = Rs[(t + 1) * B_N + b];

        float xin[4] = { xv[0] * aw0, xv[1] * aw1, xv[2] * aw2, xv[3] * aw3 };
        float dr = DT_ * Rcur;
        float k1n = k1 * no, k2n = k2 * no, k4n = k4 * no, k5n = k5 * no;
#pragma unroll
        for (int c = 0; c < 4; ++c) {
            float hx = fmaf(k2n, xin[c], fmaf(k0, xin[c], k1n));
            ex[c] = fmaxf(fmaf(ex[c], OMAW, fmaf(dr, hx, bwx[c])), 0.0f);
        }
#pragma unroll
        for (int c = 0; c < 8; ++c) {
            float hh = fmaf(k5n, outp[c], fmaf(k3, outp[c], k4n));
            float a = se[c] * OMAW, p = fmaf(dr, hh, bwh[c]);
            float r;
            if (c <= 5)      r = fmaxf(a + p, 0.0f);
            else if (c == 7) r = fminf(a - p, 0.0f);
            else             r = (lane <= 24) ? fmaxf(a + p, 0.0f)
                                              : fminf(a - p, 0.0f);
            if (c == c_d && lane == dl) r = 0.0f;   // keep diagonal at 0
            se[c] = r;
        }

        // ---- wave 0: poll h = lane+64c, each on its private line ----
        if (wid == 0) {
            const u32 want = (u32)(t + 1);
            float v[8];
            u32 done = 0;
            while (true) {
#pragma unroll
                for (int c = 0; c < 8; ++c) {
                    if (!((done >> c) & 1u)) {
                        u64 pk = ld64_agent(vrow + (size_t)(lane + 64 * c) * VSTRIDE);
                        if ((u32)(pk >> 32) == want) {
                            v[c] = __uint_as_float((u32)pk);
                            done |= (1u << c);
                        }
                    }
                }
                if (__all(done == 0xFFu)) break;
                __builtin_amdgcn_s_sleep(1);   // backoff: let stores land
            }
            float* sb = s_out[t & 1];
#pragma unroll
            for (int c = 0; c < 8; ++c) sb[lane + 64 * c] = v[c];
        }
        __syncthreads();   // single barrier/step (double-buffered s_out)

        const float* sb = s_out[t & 1];
#pragma unroll
        for (int c = 0; c < 8; ++c) outp[c] = sb[lane + 64 * c];
#pragma unroll
        for (int c = 0; c < 4; ++c) xv[c] = fmaxf(xvn[c], 0.0f);
        Rcur = Rn;
    }
}

// os[t,b,o] = sum_h hs[t,b,h] * relu(W_h2o[o,h]) * exist[h]
// Separate launch: kernel boundary (dispatch-complete release + launch
// acquire) makes the plain hs stores visible to plain loads (R8-validated).
__global__ __launch_bounds__(512) void os_proj(
    const float* __restrict__ hs, const float* __restrict__ W_h2o,
    float* __restrict__ os)
{
    const int blk  = blockIdx.x;        // 0..511
    const int t    = blk >> 3;
    const int b    = blk & 7;
    const int o    = threadIdx.x >> 6;  // 0..7
    const int lane = threadIdx.x & 63;
    const float* hrow = hs + ((size_t)t * B_N + b) * H_N;
    float acc = 0.0f;
#pragma unroll
    for (int c = 0; c < 7; ++c) {       // c==7 has no exist
        int j = lane + 64 * c;
        float w = fmaxf(W_h2o[o * H_N + j], 0.0f);
        if (j >= 410) w = 0.0f;
        acc = fmaf(hrow[j], w, acc);
    }
#pragma unroll
    for (int off = 32; off >= 1; off >>= 1) acc += __shfl_xor(acc, off, 64);
    if (lane == 0) os[t * (B_N * O_N) + b * O_N + o] = acc;
}

extern "C" void kernel_launch(void* const* d_in, const int* in_sizes, int n_in,
                              void* d_out, int out_size, void* d_ws, size_t ws_size,
                              hipStream_t stream) {
    (void)in_sizes; (void)n_in; (void)out_size; (void)ws_size;
    const float* x      = (const float*)d_in[0];
    const float* Rs     = (const float*)d_in[1];
    const float* W_x2h  = (const float*)d_in[2];
    const float* W_h2h  = (const float*)d_in[3];
    const float* b_h2h  = (const float*)d_in[4];
    const float* W_h2o  = (const float*)d_in[5];
    const float* W_attn = (const float*)d_in[6];
    const float* b_attn = (const float*)d_in[7];
    const float* kappa  = (const float*)d_in[8];
    float* os = (float*)d_out;                       // [T][B][O]
    float* hs = (float*)d_out + T_N * B_N * O_N;     // [T][B][H]
    u64* vals = (u64*)d_ws;   // [2][8][512][16] u64 = 1 MB, 128B line per h

    // zero the tagged comm lines every call (tag 0 != any wanted tag 1..63)
    hipMemsetAsync(d_ws, 0,
                   (size_t)2 * B_N * H_N * VSTRIDE * sizeof(u64), stream);
    rnn_scan<<<dim3(256), dim3(1024), 0, stream>>>(
        x, Rs, W_x2h, W_h2h, b_h2h, W_attn, b_attn, kappa, hs, vals);
    os_proj<<<dim3(512), dim3(512), 0, stream>>>(hs, W_h2o, os);
}